// Round 6
// baseline (56.444 us; speedup 1.0000x reference)
//
#include <hip/hip_runtime.h>
#include <hip/hip_bf16.h>

// YOLO layer decode: x (16, 340, 76, 76) f32 -> out (16, 4*76*76, 85) f32.
// Per (b, a, y) slab split into two x-tiles (40 + 36): transpose
// [c=85][x=W] -> [x=W][c=85] via LDS. float4 global loads (rows 16B-aligned
// at x0 = 0 and 40), fast transcendentals, 256-thread blocks, 13.6 KB LDS
// -> 8 blocks/CU (32 waves, 100% cap). Nontemporal output stores to keep
// the input resident in L3.

constexpr int BS = 16;
constexpr int NA = 4;
constexpr int NC = 85;
constexpr int FY = 76;
constexpr int FX = 76;
constexpr int PLANE = FY * FX;        // 5776
constexpr int TILE  = NC * FX;        // 6460 floats per slab
constexpr float STRIDE_F = 8.0f;
constexpr float LOG2E = 1.4426950408889634f;

typedef float f32x4 __attribute__((ext_vector_type(4)));   // native vec for nontemporal

__device__ __forceinline__ float fast_sigmoid(float v) {
    return __builtin_amdgcn_rcpf(1.0f + __builtin_amdgcn_exp2f(v * -LOG2E));
}
__device__ __forceinline__ float fast_exp(float v) {
    return __builtin_amdgcn_exp2f(v * LOG2E);
}

// Process one x-tile [X0, X0+W) of a (b,a,y) slab. W % 4 == 0, X0 % 4 == 0.
template<int W, int X0>
__device__ __forceinline__ void do_tile(const float* __restrict__ inbase,
                                        float* __restrict__ lds,
                                        float* __restrict__ outtile,
                                        float ax, float ay, float yf, int tid) {
    constexpr int RV = W / 4;          // float4s per row
    constexpr int NV = NC * RV;        // float4s per tile

    // --- Phase 1: c in [0,4): 4 rows x RV float4s = W vectors (< 256). ---
    if (tid < 4 * RV) {
        const int c = tid / RV;
        const int j = tid - c * RV;
        const float4 v = *(const float4*)(inbase + (size_t)c * PLANE + X0 + j * 4);
        const float vv[4] = {v.x, v.y, v.z, v.w};
        float r[4];
        #pragma unroll
        for (int k = 0; k < 4; ++k) {
            const int xi = X0 + 4 * j + k;      // global x for the x-shift
            float rr;
            if (c == 0)      rr = fast_sigmoid(vv[k]) * STRIDE_F + (float)xi * STRIDE_F;
            else if (c == 1) rr = fast_sigmoid(vv[k]) * STRIDE_F + yf * STRIDE_F;
            else if (c == 2) rr = fast_exp(vv[k]) * ax;
            else             rr = fast_exp(vv[k]) * ay;
            r[k] = rr;
        }
        #pragma unroll
        for (int k = 0; k < 4; ++k)
            lds[(4 * j + k) * NC + c] = r[k];
    }

    // --- Phase 2: c in [4,85): pure sigmoid, compile-time magic-div. ---
    for (int i = 4 * RV + tid; i < NV; i += 256) {
        const int c = i / RV;
        const int j = i - c * RV;
        const float4 v = *(const float4*)(inbase + (size_t)c * PLANE + X0 + j * 4);
        float* __restrict__ dst = &lds[(4 * j) * NC + c];
        dst[0 * NC] = fast_sigmoid(v.x);
        dst[1 * NC] = fast_sigmoid(v.y);
        dst[2 * NC] = fast_sigmoid(v.z);
        dst[3 * NC] = fast_sigmoid(v.w);
    }

    __syncthreads();

    // --- Store: W*85 contiguous floats, 16B-aligned base. Nontemporal. ---
    const f32x4* __restrict__ ldsv = (const f32x4*)lds;
    f32x4* __restrict__ ov = (f32x4*)outtile;
    for (int i = tid; i < NV; i += 256) {
        __builtin_nontemporal_store(ldsv[i], &ov[i]);
    }
}

__global__ __launch_bounds__(256)
void yolo_decode_kernel(const float* __restrict__ x,
                        const float* __restrict__ anchors,
                        float* __restrict__ out) {
    __shared__ float lds[40 * NC];    // max tile: 40 x 85 = 13600 B

    const int slab = blockIdx.x >> 1; // (b*NA + a)*FY + y
    const int half = blockIdx.x & 1;
    const int y    = slab % FY;
    const int ba   = slab / FY;
    const int a    = ba % NA;

    const float ax = anchors[a * 2 + 0] * STRIDE_F;
    const float ay = anchors[a * 2 + 1] * STRIDE_F;
    const float yf = (float)y;

    const float* __restrict__ inbase = x + (size_t)ba * NC * PLANE + (size_t)y * FX;
    float* __restrict__ outslab = out + (size_t)slab * TILE;
    const int tid = threadIdx.x;

    if (half == 0) {
        do_tile<40, 0>(inbase, lds, outslab + 0 * NC, ax, ay, yf, tid);
    } else {
        do_tile<36, 40>(inbase, lds, outslab + 40 * NC, ax, ay, yf, tid);
    }
}

extern "C" void kernel_launch(void* const* d_in, const int* in_sizes, int n_in,
                              void* d_out, int out_size, void* d_ws, size_t ws_size,
                              hipStream_t stream) {
    const float* x       = (const float*)d_in[0];
    const float* anchors = (const float*)d_in[1];
    float* out           = (float*)d_out;

    const int nblocks = BS * NA * FY * 2;   // 9728
    yolo_decode_kernel<<<nblocks, 256, 0, stream>>>(x, anchors, out);
}

// Round 7
// 49.777 us; speedup vs baseline: 1.1339x; 1.1339x over previous
//
#include <hip/hip_runtime.h>
#include <hip/hip_bf16.h>

// YOLO layer decode: x (16, 340, 76, 76) f32 -> out (16, 4*76*76, 85) f32.
// One (b,a,y) slab per block: transpose [c=85][x=76] -> [x=76][c=85] via LDS.
// Key lever this round: explicit MLP — each thread issues its 3-4 independent
// float4 global loads back-to-back into registers BEFORE transforming, so
// loads overlap instead of serializing on vmcnt(0) (round 4/6 compiled to
// VGPR_Count=8 => ~1 load in flight).

constexpr int BS = 16;
constexpr int NA = 4;
constexpr int NC = 85;
constexpr int FY = 76;
constexpr int FX = 76;
constexpr int PLANE = FY * FX;        // 5776
constexpr int TILE  = NC * FX;        // 6460 floats per slab
constexpr int RV    = FX / 4;         // 19 float4s per row
constexpr int NV    = NC * RV;        // 1615 float4s per slab
constexpr int NTHR  = 512;
constexpr int FULL  = 3 * NTHR;       // 1536 vectors covered by k=0..2
constexpr int TAIL  = NV - FULL;      // 79 vectors, threads 0..78
constexpr float STRIDE_F = 8.0f;
constexpr float LOG2E = 1.4426950408889634f;

__device__ __forceinline__ float fast_sigmoid(float v) {
    return __builtin_amdgcn_rcpf(1.0f + __builtin_amdgcn_exp2f(v * -LOG2E));
}
__device__ __forceinline__ float fast_exp(float v) {
    return __builtin_amdgcn_exp2f(v * LOG2E);
}

__global__ __launch_bounds__(NTHR)
void yolo_decode_kernel(const float* __restrict__ x,
                        const float* __restrict__ anchors,
                        float* __restrict__ out) {
    __shared__ float lds[TILE];       // [x][c], flat: x*NC + c  (25840 B)

    const int blk = blockIdx.x;       // (b*NA + a)*FY + y
    const int y   = blk % FY;
    const int ba  = blk / FY;
    const int a   = ba % NA;

    const float ax = anchors[a * 2 + 0] * STRIDE_F;
    const float ay = anchors[a * 2 + 1] * STRIDE_F;
    const float yf = (float)y;

    const float* __restrict__ inbase = x + (size_t)ba * NC * PLANE + (size_t)y * FX;
    const int t = threadIdx.x;

    // --- Load phase: issue all loads back-to-back (maximize vmcnt depth). ---
    float4 v[4];
    #pragma unroll
    for (int k = 0; k < 3; ++k) {
        const int i = t + NTHR * k;           // < 1536
        const int c = i / RV;                 // magic-mul
        const int j = i - c * RV;
        v[k] = *(const float4*)(inbase + (size_t)c * PLANE + j * 4);
    }
    if (t < TAIL) {
        const int i = FULL + t;
        const int c = i / RV;
        const int j = i - c * RV;
        v[3] = *(const float4*)(inbase + (size_t)c * PLANE + j * 4);
    }

    // --- Transform + LDS scatter (stride-85 rows). ---
    #pragma unroll
    for (int k = 0; k < 4; ++k) {
        if (k < 3 || t < TAIL) {
            const int i = (k < 3) ? (t + NTHR * k) : (FULL + t);
            const int c = i / RV;
            const int j = i - c * RV;
            const float vv[4] = {v[k].x, v[k].y, v[k].z, v[k].w};
            float* __restrict__ dst = &lds[(4 * j) * NC + c];
            if (c >= 4) {
                #pragma unroll
                for (int kk = 0; kk < 4; ++kk)
                    dst[kk * NC] = fast_sigmoid(vv[kk]);
            } else if (c == 0) {
                #pragma unroll
                for (int kk = 0; kk < 4; ++kk)
                    dst[kk * NC] = fast_sigmoid(vv[kk]) * STRIDE_F
                                 + (float)(4 * j + kk) * STRIDE_F;
            } else if (c == 1) {
                #pragma unroll
                for (int kk = 0; kk < 4; ++kk)
                    dst[kk * NC] = fast_sigmoid(vv[kk]) * STRIDE_F + yf * STRIDE_F;
            } else if (c == 2) {
                #pragma unroll
                for (int kk = 0; kk < 4; ++kk)
                    dst[kk * NC] = fast_exp(vv[kk]) * ax;
            } else {
                #pragma unroll
                for (int kk = 0; kk < 4; ++kk)
                    dst[kk * NC] = fast_exp(vv[kk]) * ay;
            }
        }
    }

    __syncthreads();

    // --- Store: contiguous 6460 floats (1615 float4s), 16B-aligned base. ---
    const float4* __restrict__ ldsv = (const float4*)lds;
    float4* __restrict__ ov = (float4*)(out + (size_t)blk * TILE);
    #pragma unroll
    for (int k = 0; k < 3; ++k)
        ov[t + NTHR * k] = ldsv[t + NTHR * k];
    if (t < TAIL)
        ov[FULL + t] = ldsv[FULL + t];
}

extern "C" void kernel_launch(void* const* d_in, const int* in_sizes, int n_in,
                              void* d_out, int out_size, void* d_ws, size_t ws_size,
                              hipStream_t stream) {
    const float* x       = (const float*)d_in[0];
    const float* anchors = (const float*)d_in[1];
    float* out           = (float*)d_out;

    const int nblocks = BS * NA * FY;   // 4864
    yolo_decode_kernel<<<nblocks, NTHR, 0, stream>>>(x, anchors, out);
}